// Round 1
// baseline (22433.701 us; speedup 1.0000x reference)
//
#include <hip/hip_runtime.h>
#include <hip/hip_bf16.h>

typedef unsigned short u16;
typedef unsigned int u32;
typedef __attribute__((ext_vector_type(8))) short short8;
typedef __attribute__((ext_vector_type(4))) short short4v;
typedef __attribute__((ext_vector_type(4))) float float4v;

#define Bsz 64
#define Tsz 512
#define Fsz 128
#define Usz 512
#define Gsz 2048
#define Msz 32768
#define OUTW 1152
#define BINW 640

__device__ __forceinline__ u16 f2b(float f) {
  u32 u = __float_as_uint(f);
  u32 r = (u + 0x7fffu + ((u >> 16) & 1u)) >> 16;
  return (u16)r;
}
__device__ __forceinline__ float b2f(u16 h) {
  return __uint_as_float(((u32)h) << 16);
}
__device__ __forceinline__ float sigm(float x) { return 1.f / (1.f + __expf(-x)); }
__device__ __forceinline__ float tanhfast(float x) { return 2.f / (1.f + __expf(-2.f * x)) - 1.f; }

// ---------------- weight transpose + bf16 convert: dst[n][k] = bf16(src[k][n]) ----
__global__ void k_wt(const float* __restrict__ src, u16* __restrict__ dst, int K, int N) {
  __shared__ float t[32][33];
  int k0 = blockIdx.y << 5, n0 = blockIdx.x << 5;
  int tid = threadIdx.x;
  int r = tid >> 3, c = (tid & 7) << 2;
  float4v v = *(const float4v*)(src + (size_t)(k0 + r) * N + n0 + c);
  t[r][c + 0] = v[0]; t[r][c + 1] = v[1]; t[r][c + 2] = v[2]; t[r][c + 3] = v[3];
  __syncthreads();
  short4v o;
  o[0] = (short)f2b(t[c + 0][r]);
  o[1] = (short)f2b(t[c + 1][r]);
  o[2] = (short)f2b(t[c + 2][r]);
  o[3] = (short)f2b(t[c + 3][r]);
  *(short4v*)(dst + (size_t)(n0 + r) * K + k0 + c) = o;
}

// ---------------- copy x into d_out cols [0,128) and bin (bf16) cols [0,128) ------
__global__ void k_cvx(const float* __restrict__ x, float* __restrict__ dout, u16* __restrict__ bin) {
  int id = blockIdx.x * 256 + threadIdx.x;  // 32768 rows * 32 quads
  int row = id >> 5, c = (id & 31) << 2;
  float4v v = *(const float4v*)(x + (size_t)row * Fsz + c);
  *(float4v*)(dout + (size_t)row * OUTW + c) = v;
  short4v o;
  o[0] = (short)f2b(v[0]); o[1] = (short)f2b(v[1]);
  o[2] = (short)f2b(v[2]); o[3] = (short)f2b(v[3]);
  *(short4v*)(bin + (size_t)row * BINW + c) = o;
}

// ---------------- bf16 MFMA GEMM: C[m][n] = bf16( A[m][k] * Bt[n][k] + bias[n] ) --
// tile 128x64, 256 threads (4 waves), BK=32
__launch_bounds__(256)
__global__ void k_gemm(const u16* __restrict__ A, int lda,
                       const u16* __restrict__ Bt, int K, int N,
                       const float* __restrict__ bias,
                       u16* __restrict__ C) {
  __shared__ u16 Al[128][40];
  __shared__ u16 Bl[64][40];
  int tid = threadIdx.x;
  int lane = tid & 63, wid = tid >> 6;
  int n0 = blockIdx.x << 6;
  size_t m0 = (size_t)blockIdx.y << 7;
  int mr = lane & 15, ko = (lane >> 4) << 3;
  float4v acc[2][4];
#pragma unroll
  for (int i = 0; i < 2; ++i)
#pragma unroll
    for (int j = 0; j < 4; ++j) acc[i][j] = (float4v){0.f, 0.f, 0.f, 0.f};

  for (int k0 = 0; k0 < K; k0 += 32) {
#pragma unroll
    for (int i = 0; i < 2; ++i) {
      int id = tid + (i << 8);
      int row = id >> 2, kc = (id & 3) << 3;
      *(short8*)&Al[row][kc] = *(const short8*)(A + (m0 + row) * (size_t)lda + k0 + kc);
    }
    {
      int row = tid >> 2, kc = (tid & 3) << 3;
      *(short8*)&Bl[row][kc] = *(const short8*)(Bt + (size_t)(n0 + row) * K + k0 + kc);
    }
    __syncthreads();
    short8 af0 = *(short8*)&Al[(wid << 5) + mr][ko];
    short8 af1 = *(short8*)&Al[(wid << 5) + 16 + mr][ko];
    short8 bf0 = *(short8*)&Bl[mr][ko];
    short8 bf1 = *(short8*)&Bl[16 + mr][ko];
    short8 bf2 = *(short8*)&Bl[32 + mr][ko];
    short8 bf3 = *(short8*)&Bl[48 + mr][ko];
    acc[0][0] = __builtin_amdgcn_mfma_f32_16x16x32_bf16(af0, bf0, acc[0][0], 0, 0, 0);
    acc[0][1] = __builtin_amdgcn_mfma_f32_16x16x32_bf16(af0, bf1, acc[0][1], 0, 0, 0);
    acc[0][2] = __builtin_amdgcn_mfma_f32_16x16x32_bf16(af0, bf2, acc[0][2], 0, 0, 0);
    acc[0][3] = __builtin_amdgcn_mfma_f32_16x16x32_bf16(af0, bf3, acc[0][3], 0, 0, 0);
    acc[1][0] = __builtin_amdgcn_mfma_f32_16x16x32_bf16(af1, bf0, acc[1][0], 0, 0, 0);
    acc[1][1] = __builtin_amdgcn_mfma_f32_16x16x32_bf16(af1, bf1, acc[1][1], 0, 0, 0);
    acc[1][2] = __builtin_amdgcn_mfma_f32_16x16x32_bf16(af1, bf2, acc[1][2], 0, 0, 0);
    acc[1][3] = __builtin_amdgcn_mfma_f32_16x16x32_bf16(af1, bf3, acc[1][3], 0, 0, 0);
    __syncthreads();
  }
  int rbase = (lane >> 4) << 2;
#pragma unroll
  for (int mt = 0; mt < 2; ++mt)
#pragma unroll
    for (int nt = 0; nt < 4; ++nt) {
      int n = n0 + (nt << 4) + mr;
      float bv = bias[n];
#pragma unroll
      for (int r = 0; r < 4; ++r) {
        size_t m = m0 + (wid << 5) + (mt << 4) + rbase + r;
        C[m * N + n] = f2b(acc[mt][nt][r] + bv);
      }
    }
}

// ---------------- zero scratch (h double-buffer + barrier counter) ----------------
__global__ void k_zero(u32* __restrict__ p, int n32) {
  int id = blockIdx.x * 256 + threadIdx.x;
  for (int i = id; i < n32; i += gridDim.x * 256) p[i] = 0u;
}

// ---------------- persistent LSTM scan ---------------------------------------------
// 64 WGs x 256 threads. WG b owns units [8b, 8b+8). Computes z^T = U^T * h via MFMA
// with M-rows ordered (unit*4 + gate) so each lane holds all 4 gates of one
// (unit,batch). U^T fragments live in registers for the whole scan.
__launch_bounds__(256, 1)
__global__ void k_scan(const u16* __restrict__ xw,
                       const u16* __restrict__ Ut,
                       u16* __restrict__ hn,   // 2 buffers of [64][512] bf16
                       u16* __restrict__ hseq, // [64*512][512] bf16
                       u32* __restrict__ bar) {
  int tid = threadIdx.x;
  int lane = tid & 63, wid = tid >> 6;
  int u0 = blockIdx.x << 3;
  int mr = lane & 15;
  int gate = mr & 3, du = mr >> 2;
  int ko = (lane >> 4) << 3;
  int cg = lane >> 4;

  // preload U^T fragments (constant across steps) into registers: 128 VGPRs
  short8 af[2][16];
#pragma unroll
  for (int mt = 0; mt < 2; ++mt) {
    size_t urow = (size_t)(gate * Usz + u0 + (mt << 2) + du) * Usz;
#pragma unroll
    for (int kk = 0; kk < 16; ++kk)
      af[mt][kk] = *(const short8*)(Ut + urow + (kk << 5) + ko);
  }

  int bb = (wid << 4) + mr;      // batch this lane owns (C col)
  int u_0 = u0 + cg, u_1 = u0 + 4 + cg;
  float c0 = 0.f, c1 = 0.f;

  float xv[2][4];
#pragma unroll
  for (int g = 0; g < 4; ++g) {
    xv[0][g] = b2f(xw[((size_t)bb * Tsz) * Gsz + g * Usz + u_0]);
    xv[1][g] = b2f(xw[((size_t)bb * Tsz) * Gsz + g * Usz + u_1]);
  }

  for (int t = 0; t < Tsz; ++t) {
    const u16* hr = hn + ((t & 1) ? 32768 : 0);
    u16* hwbuf = hn + ((t & 1) ? 0 : 32768);

    float4v a0 = (float4v){0.f, 0.f, 0.f, 0.f};
    float4v a1 = (float4v){0.f, 0.f, 0.f, 0.f};
#pragma unroll
    for (int kk = 0; kk < 16; ++kk) {
      short8 bf = *(const short8*)(hr + bb * Usz + (kk << 5) + ko);
      a0 = __builtin_amdgcn_mfma_f32_16x16x32_bf16(af[0][kk], bf, a0, 0, 0, 0);
      a1 = __builtin_amdgcn_mfma_f32_16x16x32_bf16(af[1][kk], bf, a1, 0, 0, 0);
    }

    // prefetch next step's xw (hides HBM latency across barrier)
    float xn[2][4];
    if (t + 1 < Tsz) {
#pragma unroll
      for (int g = 0; g < 4; ++g) {
        xn[0][g] = b2f(xw[((size_t)bb * Tsz + t + 1) * Gsz + g * Usz + u_0]);
        xn[1][g] = b2f(xw[((size_t)bb * Tsz + t + 1) * Gsz + g * Usz + u_1]);
      }
    }

    {
      float zi = a0[0] + xv[0][0], zf = a0[1] + xv[0][1];
      float zg = a0[2] + xv[0][2], zo = a0[3] + xv[0][3];
      c0 = sigm(zf) * c0 + sigm(zi) * tanhfast(zg);
      float h = sigm(zo) * tanhfast(c0);
      u16 hb = f2b(h);
      hwbuf[bb * Usz + u_0] = hb;
      hseq[((size_t)bb * Tsz + t) * Usz + u_0] = hb;
    }
    {
      float zi = a1[0] + xv[1][0], zf = a1[1] + xv[1][1];
      float zg = a1[2] + xv[1][2], zo = a1[3] + xv[1][3];
      c1 = sigm(zf) * c1 + sigm(zi) * tanhfast(zg);
      float h = sigm(zo) * tanhfast(c1);
      u16 hb = f2b(h);
      hwbuf[bb * Usz + u_1] = hb;
      hseq[((size_t)bb * Tsz + t) * Usz + u_1] = hb;
    }
    if (t + 1 < Tsz) {
#pragma unroll
      for (int g = 0; g < 4; ++g) { xv[0][g] = xn[0][g]; xv[1][g] = xn[1][g]; }
    }

    // device-scope barrier across 64 WGs (monotonic counter, no reset race)
    __syncthreads();   // drains this WG's global stores (vmcnt 0 before s_barrier)
    if (tid == 0) {
      __threadfence(); // release: write back L2 so other XCDs see h writes
      __hip_atomic_fetch_add(bar, 1u, __ATOMIC_RELEASE, __HIP_MEMORY_SCOPE_AGENT);
      u32 target = 64u * (u32)(t + 1);
      while (__hip_atomic_load(bar, __ATOMIC_ACQUIRE, __HIP_MEMORY_SCOPE_AGENT) < target)
        __builtin_amdgcn_s_sleep(1);
      __threadfence(); // acquire: invalidate L1/L2 so h reads are fresh
    }
    __syncthreads();
  }
}

// ---------------- row LayerNorm (bf16 in -> bf16 out) ------------------------------
__launch_bounds__(256)
__global__ void k_ln(const u16* __restrict__ in, const float* __restrict__ g,
                     const float* __restrict__ be, u16* __restrict__ out) {
  int lane = threadIdx.x & 63, wid = threadIdx.x >> 6;
  size_t row = (size_t)blockIdx.x * 4 + wid;
  short8 v = *(const short8*)(in + row * Usz + (lane << 3));
  float f[8];
  float s = 0.f, q = 0.f;
#pragma unroll
  for (int j = 0; j < 8; ++j) { f[j] = b2f((u16)v[j]); s += f[j]; q += f[j] * f[j]; }
#pragma unroll
  for (int o = 32; o > 0; o >>= 1) { s += __shfl_xor(s, o); q += __shfl_xor(q, o); }
  float mean = s * (1.f / 512.f);
  float var = q * (1.f / 512.f) - mean * mean;
  float rs = rsqrtf(var + 1e-3f);
  float4v g0 = *(const float4v*)(g + (lane << 3));
  float4v g1 = *(const float4v*)(g + (lane << 3) + 4);
  float4v e0 = *(const float4v*)(be + (lane << 3));
  float4v e1 = *(const float4v*)(be + (lane << 3) + 4);
  short8 o8;
#pragma unroll
  for (int j = 0; j < 8; ++j) {
    float gg = (j < 4) ? g0[j] : g1[j - 4];
    float ee = (j < 4) ? e0[j] : e1[j - 4];
    o8[j] = (short)f2b((f[j] - mean) * rs * gg + ee);
  }
  *(short8*)(out + row * Usz + (lane << 3)) = o8;
}

// ---------------- LayerNorm + highway fused -----------------------------------------
// Hx = LN(hs); Tx = sigmoid(txr); hw = Hx*Tx + (1-Tx)*ob
// writes fp32 into d_out[:, dcol:dcol+512]; optionally bf16 into bin[:,128:640]
__launch_bounds__(256)
__global__ void k_lnhw(const u16* __restrict__ hs, const float* __restrict__ g,
                       const float* __restrict__ be, const u16* __restrict__ txr,
                       const u16* __restrict__ ob, float* __restrict__ dout,
                       int dcol, u16* __restrict__ bin) {
  int lane = threadIdx.x & 63, wid = threadIdx.x >> 6;
  size_t row = (size_t)blockIdx.x * 4 + wid;
  short8 v = *(const short8*)(hs + row * Usz + (lane << 3));
  float f[8];
  float s = 0.f, q = 0.f;
#pragma unroll
  for (int j = 0; j < 8; ++j) { f[j] = b2f((u16)v[j]); s += f[j]; q += f[j] * f[j]; }
#pragma unroll
  for (int o = 32; o > 0; o >>= 1) { s += __shfl_xor(s, o); q += __shfl_xor(q, o); }
  float mean = s * (1.f / 512.f);
  float var = q * (1.f / 512.f) - mean * mean;
  float rs = rsqrtf(var + 1e-3f);
  float4v g0 = *(const float4v*)(g + (lane << 3));
  float4v g1 = *(const float4v*)(g + (lane << 3) + 4);
  float4v e0 = *(const float4v*)(be + (lane << 3));
  float4v e1 = *(const float4v*)(be + (lane << 3) + 4);
  short8 tv = *(const short8*)(txr + row * Usz + (lane << 3));
  short8 ov = *(const short8*)(ob + row * Usz + (lane << 3));
  float hwv[8];
#pragma unroll
  for (int j = 0; j < 8; ++j) {
    float gg = (j < 4) ? g0[j] : g1[j - 4];
    float ee = (j < 4) ? e0[j] : e1[j - 4];
    float hx = (f[j] - mean) * rs * gg + ee;
    float tx = sigm(b2f((u16)tv[j]));
    float o_ = b2f((u16)ov[j]);
    hwv[j] = hx * tx + (1.f - tx) * o_;
  }
  float4v w0 = {hwv[0], hwv[1], hwv[2], hwv[3]};
  float4v w1 = {hwv[4], hwv[5], hwv[6], hwv[7]};
  *(float4v*)(dout + row * OUTW + dcol + (lane << 3)) = w0;
  *(float4v*)(dout + row * OUTW + dcol + (lane << 3) + 4) = w1;
  if (bin) {
    short8 hb;
#pragma unroll
    for (int j = 0; j < 8; ++j) hb[j] = (short)f2b(hwv[j]);
    *(short8*)(bin + row * BINW + 128 + (lane << 3)) = hb;
  }
}

// ====================================================================================
extern "C" void kernel_launch(void* const* d_in, const int* in_sizes, int n_in,
                              void* d_out, int out_size, void* d_ws, size_t ws_size,
                              hipStream_t stream) {
  (void)in_sizes; (void)n_in; (void)out_size; (void)ws_size;
  const float* x = (const float*)d_in[0];
  const float* W[4]  = {(const float*)d_in[1],  (const float*)d_in[6],
                        (const float*)d_in[11], (const float*)d_in[16]};
  const float* U[4]  = {(const float*)d_in[2],  (const float*)d_in[7],
                        (const float*)d_in[12], (const float*)d_in[17]};
  const float* bb_[4] = {(const float*)d_in[3],  (const float*)d_in[8],
                        (const float*)d_in[13], (const float*)d_in[18]};
  const float* gg_[4] = {(const float*)d_in[4],  (const float*)d_in[9],
                        (const float*)d_in[14], (const float*)d_in[19]};
  const float* be_[4] = {(const float*)d_in[5],  (const float*)d_in[10],
                        (const float*)d_in[15], (const float*)d_in[20]};
  const float* Wtr[2] = {(const float*)d_in[21], (const float*)d_in[23]};
  const float* btr[2] = {(const float*)d_in[22], (const float*)d_in[24]};

  char* ws = (char*)d_ws;
  size_t off = 0;
  u16* xwb  = (u16*)(ws + off); off += (size_t)Msz * Gsz * 2;   // 134,217,728
  u16* hseq = (u16*)(ws + off); off += (size_t)Msz * Usz * 2;   // +33,554,432
  u16* mid  = (u16*)(ws + off); off += (size_t)Msz * Usz * 2;   // +33,554,432
  u16* bin  = (u16*)(ws + off); off += (size_t)Msz * BINW * 2;  // +41,943,040
  const int KIN[4] = {128, 512, 640, 512};
  u16* Wtb[4];
  for (int i = 0; i < 4; ++i) { Wtb[i] = (u16*)(ws + off); off += (size_t)Gsz * KIN[i] * 2; }
  u16* Utb[4];
  for (int i = 0; i < 4; ++i) { Utb[i] = (u16*)(ws + off); off += (size_t)Gsz * Usz * 2; }
  u16* Wtrb[2];
  for (int i = 0; i < 2; ++i) { Wtrb[i] = (u16*)(ws + off); off += (size_t)Usz * Usz * 2; }
  u16* hn = (u16*)(ws + off); off += 2 * (size_t)Bsz * Usz * 2; // double buffer 131,072
  u32* bar = (u32*)(ws + off); off += 256;
  float* dout = (float*)d_out;

  // weight prep: transpose + bf16
  for (int i = 0; i < 4; ++i)
    k_wt<<<dim3(Gsz / 32, KIN[i] / 32), 256, 0, stream>>>(W[i], Wtb[i], KIN[i], Gsz);
  for (int i = 0; i < 4; ++i)
    k_wt<<<dim3(Gsz / 32, Usz / 32), 256, 0, stream>>>(U[i], Utb[i], Usz, Gsz);
  for (int i = 0; i < 2; ++i)
    k_wt<<<dim3(Usz / 32, Usz / 32), 256, 0, stream>>>(Wtr[i], Wtrb[i], Usz, Usz);

  k_cvx<<<(Msz * 32) / 256, 256, 0, stream>>>(x, dout, bin);

  for (int blk = 0; blk < 2; ++blk) {
    int l0 = blk * 2, l1 = blk * 2 + 1;
    // layer 0: xW GEMM -> scan -> LN
    k_gemm<<<dim3(Gsz / 64, Msz / 128), 256, 0, stream>>>(bin, BINW, Wtb[l0], KIN[l0], Gsz, bb_[l0], xwb);
    k_zero<<<32, 256, 0, stream>>>((u32*)hn, 32768 + 64);
    k_scan<<<64, 256, 0, stream>>>(xwb, Utb[l0], hn, hseq, bar);
    k_ln<<<Msz / 4, 256, 0, stream>>>(hseq, gg_[l0], be_[l0], mid);
    // layer 1: xW GEMM -> scan
    k_gemm<<<dim3(Gsz / 64, Msz / 128), 256, 0, stream>>>(mid, Usz, Wtb[l1], Usz, Gsz, bb_[l1], xwb);
    k_zero<<<32, 256, 0, stream>>>((u32*)hn, 32768 + 64);
    k_scan<<<64, 256, 0, stream>>>(xwb, Utb[l1], hn, hseq, bar);
    // highway transform gate: Tx_raw = mid @ Wtr + btr (into xw scratch, done with it)
    k_gemm<<<dim3(Usz / 64, Msz / 128), 256, 0, stream>>>(mid, Usz, Wtrb[blk], Usz, Usz, btr[blk], xwb);
    // LN + highway, write fp32 output slice (+ bf16 into bin for block 1 input)
    k_lnhw<<<Msz / 4, 256, 0, stream>>>(hseq, gg_[l1], be_[l1], xwb, mid, dout,
                                        blk == 0 ? 128 : 640, blk == 0 ? bin : (u16*)nullptr);
  }
}

// Round 2
// 13093.474 us; speedup vs baseline: 1.7133x; 1.7133x over previous
//
#include <hip/hip_runtime.h>
#include <hip/hip_bf16.h>

typedef unsigned short u16;
typedef unsigned int u32;
typedef __attribute__((ext_vector_type(8))) short short8;
typedef __attribute__((ext_vector_type(4))) short short4v;
typedef __attribute__((ext_vector_type(4))) float float4v;

#define Bsz 64
#define Tsz 512
#define Fsz 128
#define Usz 512
#define Gsz 2048
#define Msz 32768
#define OUTW 1152
#define BINW 640
#define NWG 16   // scan workgroups (barrier participants)

__device__ __forceinline__ u16 f2b(float f) {
  u32 u = __float_as_uint(f);
  u32 r = (u + 0x7fffu + ((u >> 16) & 1u)) >> 16;
  return (u16)r;
}
__device__ __forceinline__ float b2f(u16 h) {
  return __uint_as_float(((u32)h) << 16);
}
__device__ __forceinline__ float sigm(float x) { return 1.f / (1.f + __expf(-x)); }
__device__ __forceinline__ float tanhfast(float x) { return 2.f / (1.f + __expf(-2.f * x)) - 1.f; }

// ---------------- weight transpose + bf16 convert: dst[n][k] = bf16(src[k][n]) ----
__global__ void k_wt(const float* __restrict__ src, u16* __restrict__ dst, int K, int N) {
  __shared__ float t[32][33];
  int k0 = blockIdx.y << 5, n0 = blockIdx.x << 5;
  int tid = threadIdx.x;
  int r = tid >> 3, c = (tid & 7) << 2;
  float4v v = *(const float4v*)(src + (size_t)(k0 + r) * N + n0 + c);
  t[r][c + 0] = v[0]; t[r][c + 1] = v[1]; t[r][c + 2] = v[2]; t[r][c + 3] = v[3];
  __syncthreads();
  short4v o;
  o[0] = (short)f2b(t[c + 0][r]);
  o[1] = (short)f2b(t[c + 1][r]);
  o[2] = (short)f2b(t[c + 2][r]);
  o[3] = (short)f2b(t[c + 3][r]);
  *(short4v*)(dst + (size_t)(n0 + r) * K + k0 + c) = o;
}

// ---------------- copy x into d_out cols [0,128) and bin (bf16) cols [0,128) ------
__global__ void k_cvx(const float* __restrict__ x, float* __restrict__ dout, u16* __restrict__ bin) {
  int id = blockIdx.x * 256 + threadIdx.x;
  int row = id >> 5, c = (id & 31) << 2;
  float4v v = *(const float4v*)(x + (size_t)row * Fsz + c);
  *(float4v*)(dout + (size_t)row * OUTW + c) = v;
  short4v o;
  o[0] = (short)f2b(v[0]); o[1] = (short)f2b(v[1]);
  o[2] = (short)f2b(v[2]); o[3] = (short)f2b(v[3]);
  *(short4v*)(bin + (size_t)row * BINW + c) = o;
}

// ---------------- bf16 MFMA GEMM: C = A * Bt^T + bias ------------------------------
// PERM=0: A rows = m, C[m][n] standard.
// PERM=1: logical row m = (b = m&63, t = m>>6); A physical row = b*512+t;
//         C written to xw2 layout: [t][u][g][b] with n = g*512+u.
template <int PERM>
__launch_bounds__(256)
__global__ void k_gemm(const u16* __restrict__ A, int lda,
                       const u16* __restrict__ Bt, int K, int N,
                       const float* __restrict__ bias,
                       u16* __restrict__ C) {
  __shared__ u16 Al[128][40];
  __shared__ u16 Bl[64][40];
  int tid = threadIdx.x;
  int lane = tid & 63, wid = tid >> 6;
  int n0 = blockIdx.x << 6;
  size_t m0 = (size_t)blockIdx.y << 7;
  int mr = lane & 15, ko = (lane >> 4) << 3;
  float4v acc[2][4];
#pragma unroll
  for (int i = 0; i < 2; ++i)
#pragma unroll
    for (int j = 0; j < 4; ++j) acc[i][j] = (float4v){0.f, 0.f, 0.f, 0.f};

  for (int k0 = 0; k0 < K; k0 += 32) {
#pragma unroll
    for (int i = 0; i < 2; ++i) {
      int id = tid + (i << 8);
      int row = id >> 2, kc = (id & 3) << 3;
      int mlog = (int)m0 + row;
      size_t rp = PERM ? ((size_t)(mlog & 63) << 9) + (mlog >> 6) : (size_t)mlog;
      *(short8*)&Al[row][kc] = *(const short8*)(A + rp * (size_t)lda + k0 + kc);
    }
    {
      int row = tid >> 2, kc = (tid & 3) << 3;
      *(short8*)&Bl[row][kc] = *(const short8*)(Bt + (size_t)(n0 + row) * K + k0 + kc);
    }
    __syncthreads();
    short8 af0 = *(short8*)&Al[(wid << 5) + mr][ko];
    short8 af1 = *(short8*)&Al[(wid << 5) + 16 + mr][ko];
    short8 bf0 = *(short8*)&Bl[mr][ko];
    short8 bf1 = *(short8*)&Bl[16 + mr][ko];
    short8 bf2 = *(short8*)&Bl[32 + mr][ko];
    short8 bf3 = *(short8*)&Bl[48 + mr][ko];
    acc[0][0] = __builtin_amdgcn_mfma_f32_16x16x32_bf16(af0, bf0, acc[0][0], 0, 0, 0);
    acc[0][1] = __builtin_amdgcn_mfma_f32_16x16x32_bf16(af0, bf1, acc[0][1], 0, 0, 0);
    acc[0][2] = __builtin_amdgcn_mfma_f32_16x16x32_bf16(af0, bf2, acc[0][2], 0, 0, 0);
    acc[0][3] = __builtin_amdgcn_mfma_f32_16x16x32_bf16(af0, bf3, acc[0][3], 0, 0, 0);
    acc[1][0] = __builtin_amdgcn_mfma_f32_16x16x32_bf16(af1, bf0, acc[1][0], 0, 0, 0);
    acc[1][1] = __builtin_amdgcn_mfma_f32_16x16x32_bf16(af1, bf1, acc[1][1], 0, 0, 0);
    acc[1][2] = __builtin_amdgcn_mfma_f32_16x16x32_bf16(af1, bf2, acc[1][2], 0, 0, 0);
    acc[1][3] = __builtin_amdgcn_mfma_f32_16x16x32_bf16(af1, bf3, acc[1][3], 0, 0, 0);
    __syncthreads();
  }
  int rbase = (lane >> 4) << 2;
#pragma unroll
  for (int mt = 0; mt < 2; ++mt)
#pragma unroll
    for (int nt = 0; nt < 4; ++nt) {
      int n = n0 + (nt << 4) + mr;
      float bv = bias[n];
#pragma unroll
      for (int r = 0; r < 4; ++r) {
        int mlog = (int)m0 + (wid << 5) + (mt << 4) + rbase + r;
        float val = acc[mt][nt][r] + bv;
        if (PERM) {
          int b = mlog & 63, tt = mlog >> 6;
          int u = n & 511, g = n >> 9;
          C[(((size_t)tt * 512 + u) * 4 + g) * 64 + b] = f2b(val);
        } else {
          C[(size_t)mlog * N + n] = f2b(val);
        }
      }
    }
}

// ---------------- zero scratch (h double-buffer + barrier counter) ----------------
__global__ void k_zero(u32* __restrict__ p, int n32) {
  int id = blockIdx.x * 256 + threadIdx.x;
  for (int i = id; i < n32; i += gridDim.x * 256) p[i] = 0u;
}

// ---------------- persistent LSTM scan ---------------------------------------------
// 16 WGs x 256 threads. WG w owns units [32w, 32w+32); wave v owns 8 units, all 64
// batches. U^T fragments in registers (128 VGPR). h[t] staged global->LDS (64KB)
// with XOR-swizzled source so ds_read_b128 B-frags are conflict-free. xw is in
// [t][u][gate][b] layout and enters via accumulator init.
__launch_bounds__(256, 1)
__global__ void k_scan(const u16* __restrict__ xw2,
                       const u16* __restrict__ Ut,
                       u16* __restrict__ hn,   // 2 buffers of [64][512] bf16
                       u16* __restrict__ hseq, // [b*T+t][512] bf16
                       u32* __restrict__ bar) {
  __shared__ u16 hl[32768];  // 64 KB staged h
  int tid = threadIdx.x;
  int lane = tid & 63, wid = tid >> 6;
  int mr = lane & 15, cg = lane >> 4;
  int ko = cg << 3;
  int gate = mr & 3, du = mr >> 2;
  int u0 = (blockIdx.x << 5) + (wid << 3);

  // preload U^T fragments (constant across steps): af[2][16] = 128 VGPRs
  short8 af[2][16];
#pragma unroll
  for (int mt = 0; mt < 2; ++mt) {
    size_t urow = (size_t)(gate * Usz + u0 + (mt << 2) + du) * Usz;
#pragma unroll
    for (int kk = 0; kk < 16; ++kk)
      af[mt][kk] = *(const short8*)(Ut + urow + (kk << 5) + ko);
  }

  float cst[2][4];
#pragma unroll
  for (int mt = 0; mt < 2; ++mt)
#pragma unroll
    for (int nt = 0; nt < 4; ++nt) cst[mt][nt] = 0.f;

  // xw values this lane needs: [mt][gate][nt]
  u16 xwv[2][4][4], xwn[2][4][4];
#pragma unroll
  for (int mt = 0; mt < 2; ++mt) {
    int u = u0 + (mt << 2) + cg;
#pragma unroll
    for (int g = 0; g < 4; ++g)
#pragma unroll
      for (int nt = 0; nt < 4; ++nt)
        xwv[mt][g][nt] = xw2[(((size_t)0 * 512 + u) * 4 + g) * 64 + (nt << 4) + mr];
  }

  for (int t = 0; t < Tsz; ++t) {
    const u16* hsrc = hn + ((t & 1) ? 32768 : 0);
    u16* hdst = hn + ((t & 1) ? 0 : 32768);

    // ---- stage h[t] (64KB) global -> LDS, source-side XOR swizzle ----
    {
      const char* src = (const char*)hsrc;
#pragma unroll
      for (int j = 0; j < 16; ++j) {
        int b = (wid << 4) + j;
        int soff = ((lane << 4) ^ ((b & 7) << 4));
        __builtin_amdgcn_global_load_lds(
            (const __attribute__((address_space(1))) void*)(src + (size_t)b * 1024 + soff),
            (__attribute__((address_space(3))) void*)((char*)hl + (b << 10)),
            16, 0, 0);
      }
    }

    // ---- prefetch next step's xw (overlaps staging + barrier) ----
    if (t + 1 < Tsz) {
#pragma unroll
      for (int mt = 0; mt < 2; ++mt) {
        int u = u0 + (mt << 2) + cg;
#pragma unroll
        for (int g = 0; g < 4; ++g)
#pragma unroll
          for (int nt = 0; nt < 4; ++nt)
            xwn[mt][g][nt] = xw2[(((size_t)(t + 1) * 512 + u) * 4 + g) * 64 + (nt << 4) + mr];
      }
    }

    // ---- init accumulators with xw (z = xw + U^T h) ----
    float4v acc[2][4];
#pragma unroll
    for (int mt = 0; mt < 2; ++mt)
#pragma unroll
      for (int nt = 0; nt < 4; ++nt)
        acc[mt][nt] = (float4v){b2f(xwv[mt][0][nt]), b2f(xwv[mt][1][nt]),
                                b2f(xwv[mt][2][nt]), b2f(xwv[mt][3][nt])};

    __syncthreads();  // drains vmcnt(0): staging + prefetch complete

    // ---- MFMA phase: 64 ds_read_b128 + 128 MFMA per wave ----
#pragma unroll
    for (int kk = 0; kk < 16; ++kk) {
      short8 bfr[4];
#pragma unroll
      for (int nt = 0; nt < 4; ++nt) {
        int b = (nt << 4) + mr;
        int addr = (b << 10) + ((((kk << 6) + (cg << 4)) ^ ((b & 7) << 4)));
        bfr[nt] = *(const short8*)((const char*)hl + addr);
      }
#pragma unroll
      for (int mt = 0; mt < 2; ++mt)
#pragma unroll
        for (int nt = 0; nt < 4; ++nt)
          acc[mt][nt] = __builtin_amdgcn_mfma_f32_16x16x32_bf16(af[mt][kk], bfr[nt], acc[mt][nt], 0, 0, 0);
    }

    // ---- gates + h stores (full-line combining within WG) ----
#pragma unroll
    for (int mt = 0; mt < 2; ++mt)
#pragma unroll
      for (int nt = 0; nt < 4; ++nt) {
        float zi = acc[mt][nt][0], zf = acc[mt][nt][1];
        float zg = acc[mt][nt][2], zo = acc[mt][nt][3];
        float c = sigm(zf) * cst[mt][nt] + sigm(zi) * tanhfast(zg);
        cst[mt][nt] = c;
        float h = sigm(zo) * tanhfast(c);
        u16 hb = f2b(h);
        int b = (nt << 4) + mr;
        int u = u0 + (mt << 2) + cg;
        hdst[(size_t)b * Usz + u] = hb;
        hseq[((size_t)b * Tsz + t) * Usz + u] = hb;
      }

    if (t + 1 < Tsz) {
#pragma unroll
      for (int mt = 0; mt < 2; ++mt)
#pragma unroll
        for (int g = 0; g < 4; ++g)
#pragma unroll
          for (int nt = 0; nt < 4; ++nt) xwv[mt][g][nt] = xwn[mt][g][nt];
    }

    // ---- device-scope barrier across 16 WGs ----
    __syncthreads();  // all waves done reading LDS + h stores drained (vmcnt0)
    if (tid == 0) {
      __threadfence();
      __hip_atomic_fetch_add(bar, 1u, __ATOMIC_RELEASE, __HIP_MEMORY_SCOPE_AGENT);
      u32 target = (u32)NWG * (u32)(t + 1);
      while (__hip_atomic_load(bar, __ATOMIC_ACQUIRE, __HIP_MEMORY_SCOPE_AGENT) < target)
        __builtin_amdgcn_s_sleep(1);
      __threadfence();
    }
    __syncthreads();
  }
}

// ---------------- row LayerNorm (bf16 in -> bf16 out) ------------------------------
__launch_bounds__(256)
__global__ void k_ln(const u16* __restrict__ in, const float* __restrict__ g,
                     const float* __restrict__ be, u16* __restrict__ out) {
  int lane = threadIdx.x & 63, wid = threadIdx.x >> 6;
  size_t row = (size_t)blockIdx.x * 4 + wid;
  short8 v = *(const short8*)(in + row * Usz + (lane << 3));
  float f[8];
  float s = 0.f, q = 0.f;
#pragma unroll
  for (int j = 0; j < 8; ++j) { f[j] = b2f((u16)v[j]); s += f[j]; q += f[j] * f[j]; }
#pragma unroll
  for (int o = 32; o > 0; o >>= 1) { s += __shfl_xor(s, o); q += __shfl_xor(q, o); }
  float mean = s * (1.f / 512.f);
  float var = q * (1.f / 512.f) - mean * mean;
  float rs = rsqrtf(var + 1e-3f);
  float4v g0 = *(const float4v*)(g + (lane << 3));
  float4v g1 = *(const float4v*)(g + (lane << 3) + 4);
  float4v e0 = *(const float4v*)(be + (lane << 3));
  float4v e1 = *(const float4v*)(be + (lane << 3) + 4);
  short8 o8;
#pragma unroll
  for (int j = 0; j < 8; ++j) {
    float gg = (j < 4) ? g0[j] : g1[j - 4];
    float ee = (j < 4) ? e0[j] : e1[j - 4];
    o8[j] = (short)f2b((f[j] - mean) * rs * gg + ee);
  }
  *(short8*)(out + row * Usz + (lane << 3)) = o8;
}

// ---------------- LayerNorm + highway fused -----------------------------------------
__launch_bounds__(256)
__global__ void k_lnhw(const u16* __restrict__ hs, const float* __restrict__ g,
                       const float* __restrict__ be, const u16* __restrict__ txr,
                       const u16* __restrict__ ob, float* __restrict__ dout,
                       int dcol, u16* __restrict__ bin) {
  int lane = threadIdx.x & 63, wid = threadIdx.x >> 6;
  size_t row = (size_t)blockIdx.x * 4 + wid;
  short8 v = *(const short8*)(hs + row * Usz + (lane << 3));
  float f[8];
  float s = 0.f, q = 0.f;
#pragma unroll
  for (int j = 0; j < 8; ++j) { f[j] = b2f((u16)v[j]); s += f[j]; q += f[j] * f[j]; }
#pragma unroll
  for (int o = 32; o > 0; o >>= 1) { s += __shfl_xor(s, o); q += __shfl_xor(q, o); }
  float mean = s * (1.f / 512.f);
  float var = q * (1.f / 512.f) - mean * mean;
  float rs = rsqrtf(var + 1e-3f);
  float4v g0 = *(const float4v*)(g + (lane << 3));
  float4v g1 = *(const float4v*)(g + (lane << 3) + 4);
  float4v e0 = *(const float4v*)(be + (lane << 3));
  float4v e1 = *(const float4v*)(be + (lane << 3) + 4);
  short8 tv = *(const short8*)(txr + row * Usz + (lane << 3));
  short8 ov = *(const short8*)(ob + row * Usz + (lane << 3));
  float hwv[8];
#pragma unroll
  for (int j = 0; j < 8; ++j) {
    float gg = (j < 4) ? g0[j] : g1[j - 4];
    float ee = (j < 4) ? e0[j] : e1[j - 4];
    float hx = (f[j] - mean) * rs * gg + ee;
    float tx = sigm(b2f((u16)tv[j]));
    float o_ = b2f((u16)ov[j]);
    hwv[j] = hx * tx + (1.f - tx) * o_;
  }
  float4v w0 = {hwv[0], hwv[1], hwv[2], hwv[3]};
  float4v w1 = {hwv[4], hwv[5], hwv[6], hwv[7]};
  *(float4v*)(dout + row * OUTW + dcol + (lane << 3)) = w0;
  *(float4v*)(dout + row * OUTW + dcol + (lane << 3) + 4) = w1;
  if (bin) {
    short8 hb;
#pragma unroll
    for (int j = 0; j < 8; ++j) hb[j] = (short)f2b(hwv[j]);
    *(short8*)(bin + row * BINW + 128 + (lane << 3)) = hb;
  }
}

// ====================================================================================
extern "C" void kernel_launch(void* const* d_in, const int* in_sizes, int n_in,
                              void* d_out, int out_size, void* d_ws, size_t ws_size,
                              hipStream_t stream) {
  (void)in_sizes; (void)n_in; (void)out_size; (void)ws_size;
  const float* x = (const float*)d_in[0];
  const float* W[4]  = {(const float*)d_in[1],  (const float*)d_in[6],
                        (const float*)d_in[11], (const float*)d_in[16]};
  const float* U[4]  = {(const float*)d_in[2],  (const float*)d_in[7],
                        (const float*)d_in[12], (const float*)d_in[17]};
  const float* bb_[4] = {(const float*)d_in[3],  (const float*)d_in[8],
                        (const float*)d_in[13], (const float*)d_in[18]};
  const float* gg_[4] = {(const float*)d_in[4],  (const float*)d_in[9],
                        (const float*)d_in[14], (const float*)d_in[19]};
  const float* be_[4] = {(const float*)d_in[5],  (const float*)d_in[10],
                        (const float*)d_in[15], (const float*)d_in[20]};
  const float* Wtr[2] = {(const float*)d_in[21], (const float*)d_in[23]};
  const float* btr[2] = {(const float*)d_in[22], (const float*)d_in[24]};

  char* ws = (char*)d_ws;
  size_t off = 0;
  u16* xwb  = (u16*)(ws + off); off += (size_t)Msz * Gsz * 2;
  u16* hseq = (u16*)(ws + off); off += (size_t)Msz * Usz * 2;
  u16* mid  = (u16*)(ws + off); off += (size_t)Msz * Usz * 2;
  u16* bin  = (u16*)(ws + off); off += (size_t)Msz * BINW * 2;
  const int KIN[4] = {128, 512, 640, 512};
  u16* Wtb[4];
  for (int i = 0; i < 4; ++i) { Wtb[i] = (u16*)(ws + off); off += (size_t)Gsz * KIN[i] * 2; }
  u16* Utb[4];
  for (int i = 0; i < 4; ++i) { Utb[i] = (u16*)(ws + off); off += (size_t)Gsz * Usz * 2; }
  u16* Wtrb[2];
  for (int i = 0; i < 2; ++i) { Wtrb[i] = (u16*)(ws + off); off += (size_t)Usz * Usz * 2; }
  u16* hn = (u16*)(ws + off); off += 2 * (size_t)Bsz * Usz * 2;
  u32* bar = (u32*)(ws + off); off += 256;
  float* dout = (float*)d_out;

  for (int i = 0; i < 4; ++i)
    k_wt<<<dim3(Gsz / 32, KIN[i] / 32), 256, 0, stream>>>(W[i], Wtb[i], KIN[i], Gsz);
  for (int i = 0; i < 4; ++i)
    k_wt<<<dim3(Gsz / 32, Usz / 32), 256, 0, stream>>>(U[i], Utb[i], Usz, Gsz);
  for (int i = 0; i < 2; ++i)
    k_wt<<<dim3(Usz / 32, Usz / 32), 256, 0, stream>>>(Wtr[i], Wtrb[i], Usz, Usz);

  k_cvx<<<(Msz * 32) / 256, 256, 0, stream>>>(x, dout, bin);

  for (int blk = 0; blk < 2; ++blk) {
    int l0 = blk * 2, l1 = blk * 2 + 1;
    // layer 0: xW GEMM (permuted out) -> scan -> LN
    k_gemm<1><<<dim3(Gsz / 64, Msz / 128), 256, 0, stream>>>(bin, BINW, Wtb[l0], KIN[l0], Gsz, bb_[l0], xwb);
    k_zero<<<32, 256, 0, stream>>>((u32*)hn, 32768 + 64);
    k_scan<<<NWG, 256, 0, stream>>>(xwb, Utb[l0], hn, hseq, bar);
    k_ln<<<Msz / 4, 256, 0, stream>>>(hseq, gg_[l0], be_[l0], mid);
    // layer 1: xW GEMM (permuted out) -> scan
    k_gemm<1><<<dim3(Gsz / 64, Msz / 128), 256, 0, stream>>>(mid, Usz, Wtb[l1], Usz, Gsz, bb_[l1], xwb);
    k_zero<<<32, 256, 0, stream>>>((u32*)hn, 32768 + 64);
    k_scan<<<NWG, 256, 0, stream>>>(xwb, Utb[l1], hn, hseq, bar);
    // highway transform gate: Tx_raw = mid @ Wtr + btr (standard layout)
    k_gemm<0><<<dim3(Usz / 64, Msz / 128), 256, 0, stream>>>(mid, Usz, Wtrb[blk], Usz, Usz, btr[blk], xwb);
    k_lnhw<<<Msz / 4, 256, 0, stream>>>(hseq, gg_[l1], be_[l1], xwb, mid, dout,
                                        blk == 0 ? 128 : 640, blk == 0 ? bin : (u16*)nullptr);
  }
}